// Round 10
// baseline (178.557 us; speedup 1.0000x reference)
//
#include <hip/hip_runtime.h>
#include <hip/hip_bf16.h>

typedef unsigned short u16;
typedef unsigned int   u32;
typedef unsigned long long u64;

#define BATCH 4096
#define IDIM  1024
#define ODIM  1024
#define NDEG  9                 // degree 8 -> 9 basis terms
#define KA    8192              // GEMM K: d=1..8 only (d=0 is rank-1)
#define KAH   (KA / 2)          // 4096 per split-K half

typedef __attribute__((ext_vector_type(8))) short short8_t;   // 8 bf16 = 4 VGPRs
typedef __attribute__((ext_vector_type(4))) float f32x4;

// round-to-nearest-even f32 -> bf16
__device__ __forceinline__ u16 f2bf(float f) {
    union { float f; u32 u; } v; v.f = f;
    u32 r = v.u + 0x7FFFu + ((v.u >> 16) & 1u);
    return (u16)(r >> 16);
}
__device__ __forceinline__ u32 pack2bf(float lo, float hi) {
    return (u32)f2bf(lo) | ((u32)f2bf(hi) << 16);
}
__device__ __forceinline__ float bf2f(u16 h) {
    union { u32 u; float f; } v; v.u = (u32)h << 16; return v.f;
}

// fast tanh via v_exp_f32 + Newton-refined v_rcp (rel err ~1e-6 << bf16 ulp)
__device__ __forceinline__ float fast_tanh(float v) {
    float c = fminf(fmaxf(v, -9.0f), 9.0f);
    float u = __builtin_amdgcn_exp2f(c * 2.8853900817779268f);  // e^(2c)
    float d = u + 1.0f;
    float r = __builtin_amdgcn_rcpf(d);
    r = r * (2.0f - d * r);
    return (u - 1.0f) * r;
}

// async 16B global -> LDS (wave-uniform LDS base + lane*16)
__device__ __forceinline__ void gl_lds16(const u16* g, u16* l) {
    __builtin_amdgcn_global_load_lds(
        (const __attribute__((address_space(1))) void*)g,
        (__attribute__((address_space(3))) void*)l,
        16, 0, 0);
}

// ---------------------------------------------------------------------------
// Fused prep (single dispatch, block-role split) — unchanged from R9.
// ---------------------------------------------------------------------------
#define PB_TI 128
#define PB_TO 8
#define PB_J  (PB_TO * NDEG)    // 72
#define PB_LS 132               // LDS row stride (u16): 264 B, u64-aligned rows

#define NB_B   1024
#define NB_A   2048

__global__ void prep_kernel(const float* __restrict__ x,
                            const float* __restrict__ c,
                            u16* __restrict__ A, u16* __restrict__ Bt,
                            float* __restrict__ Pr) {
    __shared__ u16 lds[PB_J * PB_LS];             // 19 KB (B-blocks only)
    const int bb  = blockIdx.x;
    const int tid = threadIdx.x;

    if (bb < NB_B) {
        const int i0 = (bb & 7) * PB_TI;
        const int o0 = (bb >> 3) * PB_TO;
        const float* src = c + (size_t)i0 * (ODIM * NDEG) + (size_t)o0 * NDEG;
#pragma unroll
        for (int t = 0; t < 36; ++t) {            // 9216 floats / 256 threads
            int f  = t * 256 + tid;
            int ii = f / PB_J;
            int j  = f - ii * PB_J;
            float v = src[(size_t)ii * (ODIM * NDEG) + j];
            lds[j * PB_LS + ii] = f2bf(v);
        }
        __syncthreads();

        // ---- rank-1 column sums from the d=0 LDS row ----
        {
            int o   = tid >> 5;                   // 0..7
            int sub = tid & 31;                   // 32 threads per o
            const u16* row = lds + (o * NDEG) * PB_LS + sub * 4;
            float s = bf2f(row[0]) + bf2f(row[1]) + bf2f(row[2]) + bf2f(row[3]);
#pragma unroll
            for (int m = 16; m >= 1; m >>= 1)     // stays within 32-lane halves
                s += __shfl_xor(s, m, 64);
            if (sub == 0)                         // deterministic partials
                Pr[(size_t)(bb & 7) * ODIM + o0 + o] = s;
        }

#pragma unroll
        for (int t = 0; t < 9; ++t) {             // 72*32 u64 groups / 256 thr
            int g   = t * 256 + tid;
            int j   = g >> 5;                     // 0..71
            int ii4 = (g & 31) << 2;
            int o   = j / NDEG;
            int d   = j - o * NDEG;
            if (d != 0) {
                u64 v = *(const u64*)(lds + j * PB_LS + ii4);
                *(u64*)(Bt + (size_t)(o0 + o) * KA + (d - 1) * 1024 + i0 + ii4) = v;
            }
        }
    } else {
        // ---- A basis (planes d=1..8): thread handles 8 consecutive i ----
        int t  = (bb - NB_B) * 256 + tid;         // 0..524287
        int b  = t >> 7;
        int i8 = (t & 127) << 3;
        const float4* xv = (const float4*)(x + ((size_t)t << 3));
        float4 xa = xv[0], xb = xv[1];
        float th[8] = {fast_tanh(xa.x), fast_tanh(xa.y),
                       fast_tanh(xa.z), fast_tanh(xa.w),
                       fast_tanh(xb.x), fast_tanh(xb.y),
                       fast_tanh(xb.z), fast_tanh(xb.w)};
        float va[8], vb[8];
#pragma unroll
        for (int j = 0; j < 8; ++j) { va[j] = 2.0f; vb[j] = th[j]; }
        u16* dst = A + (size_t)b * KA + i8;
        uint4 w;
        w.x = pack2bf(th[0], th[1]); w.y = pack2bf(th[2], th[3]);
        w.z = pack2bf(th[4], th[5]); w.w = pack2bf(th[6], th[7]);
        *(uint4*)dst = w;                          // d=1 plane
#pragma unroll
        for (int d = 2; d < NDEG; ++d) {
            float nx[8];
#pragma unroll
            for (int j = 0; j < 8; ++j) {
                nx[j] = th[j] * vb[j] + va[j];
                va[j] = vb[j]; vb[j] = nx[j];
            }
            w.x = pack2bf(nx[0], nx[1]); w.y = pack2bf(nx[2], nx[3]);
            w.z = pack2bf(nx[4], nx[5]); w.w = pack2bf(nx[6], nx[7]);
            *(uint4*)(dst + (size_t)(d - 1) * 1024) = w;
        }
    }
}

// ---------------------------------------------------------------------------
// GEMM: identical 2-barrier structure to R9 except BK 64 -> 128.
// Rationale [arithmetic]: R9 pays ~2760 cyc/iter x 64 iters, of which only
// ~600-1000 cyc is MFMA; the rest is the per-iteration vmcnt(0)+barrier
// drain. BK=128 halves the drain count (64 -> 32) at unchanged occupancy
// (2 blocks/CU: 128 KB LDS <= 160 KB, VGPR < 256 cap). m132's BK=128
// regression mechanism (occupancy 3 -> 2) is absent here.
// Swizzle: 16 chunks/row; XOR touches only low 3 chunk bits, so the
// reader/writer inverse and the measured-0-conflict group structure of the
// BK=64 kernel carry over unchanged.
// z=0 writes straight to out; z=1 writes the single P plane.
// ---------------------------------------------------------------------------
__global__ __launch_bounds__(256, 2)
void gemm_kernel(const u16* __restrict__ A, const u16* __restrict__ B,
                 float* __restrict__ P, float* __restrict__ out) {
    __shared__ __align__(16) u16 ldsA[128 * 128]; // 32 KB
    __shared__ __align__(16) u16 ldsB[128 * 128]; // 32 KB

    const int tid  = threadIdx.x;
    const int lane = tid & 63;
    const int wave = tid >> 6;
    const int quad = lane >> 4;
    const int l15  = lane & 15;
    const int wm   = wave & 1;
    const int wn   = wave >> 1;

    const int bid = blockIdx.x;                   // 0..511
    const int xcd = bid & 7;
    const int loc = bid >> 3;                     // 0..63
    const int z   = xcd >> 2;
    const int bm  = ((xcd & 3) << 3) | (loc >> 3);
    const int bn  = loc & 7;
    const int kStart = z * KAH;

    const u16* ga[8]; const u16* gb[8];
    u16* la[8]; u16* lb[8];
#pragma unroll
    for (int t = 0; t < 8; ++t) {
        int s  = t * 256 + tid;                   // 16B slot in tile, 0..2047
        int r  = s >> 4;                          // tile row 0..127
        int sc = (s & 15) ^ (r & 7);              // source k-chunk (XOR low 3)
        ga[t] = A + (size_t)(bm * 128 + r) * KA + kStart + sc * 8;
        gb[t] = B + (size_t)(bn * 128 + r) * KA + kStart + sc * 8;
        la[t] = ldsA + s * 8;
        lb[t] = ldsB + s * 8;
    }

    f32x4 acc[4][4];
#pragma unroll
    for (int mt = 0; mt < 4; ++mt)
#pragma unroll
        for (int nt = 0; nt < 4; ++nt)
            acc[mt][nt] = (f32x4){0.f, 0.f, 0.f, 0.f};

    const int nIter = KAH / 128;                  // 32
    for (int it = 0; it < nIter; ++it) {
#pragma unroll
        for (int t = 0; t < 8; ++t) gl_lds16(ga[t], la[t]);
#pragma unroll
        for (int t = 0; t < 8; ++t) gl_lds16(gb[t], lb[t]);
        __syncthreads();

#pragma unroll
        for (int kk = 0; kk < 4; ++kk) {
            short8_t af[4], bfg[4];
#pragma unroll
            for (int mt = 0; mt < 4; ++mt) {
                int row = wm * 64 + mt * 16 + l15;
                int pc  = (kk * 4 + quad) ^ (row & 7);
                af[mt] = *(const short8_t*)(ldsA + (row * 16 + pc) * 8);
            }
#pragma unroll
            for (int nt = 0; nt < 4; ++nt) {
                int row = wn * 64 + nt * 16 + l15;
                int pc  = (kk * 4 + quad) ^ (row & 7);
                bfg[nt] = *(const short8_t*)(ldsB + (row * 16 + pc) * 8);
            }
#pragma unroll
            for (int mt = 0; mt < 4; ++mt)
#pragma unroll
                for (int nt = 0; nt < 4; ++nt)
                    acc[mt][nt] = __builtin_amdgcn_mfma_f32_16x16x32_bf16(
                        af[mt], bfg[nt], acc[mt][nt], 0, 0, 0);
        }
        __syncthreads();

#pragma unroll
        for (int t = 0; t < 8; ++t) { ga[t] += 128; gb[t] += 128; }
    }

    // epilogue: C/D layout col = lane&15, row = quad*4 + reg  [m89-verified]
    float* C = (z == 0) ? out : P;
#pragma unroll
    for (int mt = 0; mt < 4; ++mt) {
#pragma unroll
        for (int nt = 0; nt < 4; ++nt) {
            int row0 = bm * 128 + wm * 64 + mt * 16 + quad * 4;
            int col  = bn * 128 + wn * 64 + nt * 16 + l15;
#pragma unroll
            for (int r = 0; r < 4; ++r)
                C[(size_t)(row0 + r) * ODIM + col] = acc[mt][nt][r];
        }
    }
}

// out = out(z0) + P(z1) + 2 * sum_blk Pr[blk][o]   (split-K + rank-1 d=0 term)
__global__ void reduce_kernel(const float* __restrict__ P,
                              const float* __restrict__ Pr,
                              float* __restrict__ out) {
    int t  = blockIdx.x * 256 + threadIdx.x;      // over BATCH*ODIM/4
    int o4 = t & 255;                             // f32x4 column index
    f32x4 a = ((const f32x4*)out)[t];             // z=0 partial (L3-hot)
    a += ((const f32x4*)P)[t];                    // z=1 partial (L3-hot)
    f32x4 r = (f32x4){0.f, 0.f, 0.f, 0.f};
#pragma unroll
    for (int blk = 0; blk < 8; ++blk)
        r += ((const f32x4*)Pr)[blk * 256 + o4];  // hot in L2 (32 KB table)
    ((f32x4*)out)[t] = a + r + r;                 // + 2*r  (V0 = 2)
}

extern "C" void kernel_launch(void* const* d_in, const int* in_sizes, int n_in,
                              void* d_out, int out_size, void* d_ws, size_t ws_size,
                              hipStream_t stream) {
    const float* x      = (const float*)d_in[0];   // [4096,1024] f32
    const float* coeffs = (const float*)d_in[1];   // [1024,1024,9] f32
    float* out = (float*)d_out;                    // [4096,1024] f32
    (void)ws_size;

    u16*   A  = (u16*)d_ws;                        // 67.1 MB
    u16*   Bt = A + (size_t)BATCH * KA;            // 16.8 MB
    float* Pr = (float*)(Bt + (size_t)ODIM * KA);  // 32 KB rank-1 partials
    float* P  = Pr + 8 * ODIM;                     // 16.8 MB (1 split-K plane)
    // total ws: 100.8 MB

    prep_kernel<<<NB_B + NB_A, 256, 0, stream>>>(x, coeffs, A, Bt, Pr);
    gemm_kernel<<<512, 256, 0, stream>>>(A, Bt, P, out);
    reduce_kernel<<<BATCH * ODIM / 1024, 256, 0, stream>>>(P, Pr, out);
}